// Round 1
// baseline (2591.808 us; speedup 1.0000x reference)
//
#include <hip/hip_runtime.h>
#include <hip/hip_bf16.h>

// ShardAttention: out = ((softmax(y y^T / 8) @ x) per head, concat) @ W
// B=2, T=2048, C=1024, H=16, hs=64, D=H*C=16384, E=1024.
//
// Pipeline (R0 baseline):
//   t0: xbT[b][c][t]  = bf16(x[b][t][c])           (transpose+cast)
//   t1: wbT[e][k]     = bf16(W[k][e])              (transpose+cast)
//   per (b, head-slab): scores+softmax (fp32 vector) -> P bf16
//                       PV GEMM (bf16 MFMA)         -> O bf16 [b,t,(h c)]
//   proj GEMM (bf16 MFMA): out = O @ W              -> fp32
//
// GEMM structure = m97-verified: 128x128 tile / 4 waves / BK=32 /
// global_load_lds width=16 / ds_read_b128 / mfma_f32_16x16x32_bf16.

typedef __hip_bfloat16 bf16;
typedef __bf16 bf16x8 __attribute__((ext_vector_type(8)));
typedef float f32x4 __attribute__((ext_vector_type(4)));

#define B_ 2
#define T_ 2048
#define C_ 1024
#define H_ 16
#define D_ 16384
#define E_ 1024

__device__ __forceinline__ void load_lds16(const void* g, void* l) {
  __builtin_amdgcn_global_load_lds(
      (const __attribute__((address_space(1))) void*)g,
      (__attribute__((address_space(3))) void*)l, 16, 0, 0);
}

// ---------------- transpose + fp32->bf16 cast ----------------
// out[z][c][r] = bf16(in[z][r][c]);  grid (cols/32, rows/32, Z), block (32,8)
__global__ __launch_bounds__(256) void transpose_cast_kernel(
    const float* __restrict__ in, bf16* __restrict__ out, int rows, int cols) {
  __shared__ float tile[32][33];
  size_t zoff = (size_t)blockIdx.z * rows * cols;
  int c0 = blockIdx.x * 32, r0 = blockIdx.y * 32;
  int tx = threadIdx.x, ty = threadIdx.y;
  for (int i = ty; i < 32; i += 8)
    tile[i][tx] = in[zoff + (size_t)(r0 + i) * cols + c0 + tx];
  __syncthreads();
  for (int i = ty; i < 32; i += 8)
    out[zoff + (size_t)(c0 + i) * rows + r0 + tx] = __float2bfloat16(tile[tx][i]);
}

// ---------------- scores + softmax (fp32) -> P bf16 ----------------
// One block: 8 query rows of one head. Full row (2048 scores) kept in regs
// (8 s-cols per thread). No max-subtraction: scores ~ N(0,1), diag <= ~16
// after /8 scaling, exp() safe in fp32.
// grid (T/8, Hs), block 256.  P[hh][t][s], slab of Hs heads starting at h0.
__global__ __launch_bounds__(256) void scores_softmax_kernel(
    const float* __restrict__ xb, bf16* __restrict__ P, int h0) {
  constexpr int RQ = 8;
  int t = threadIdx.x;
  int hh = blockIdx.y;
  int h = h0 + hh;
  int r0 = blockIdx.x * RQ;
  __shared__ float qs[RQ][64];
  for (int i = t; i < RQ * 64; i += 256) {
    int r = i >> 6, k = i & 63;
    qs[r][k] = xb[(size_t)(r0 + r) * C_ + h * 64 + k];
  }
  __syncthreads();

  float ex[8][RQ];
#pragma unroll
  for (int si = 0; si < 8; ++si) {
    int s = si * 256 + t;
    const float4* kp = (const float4*)(xb + (size_t)s * C_ + h * 64);
    float d[RQ];
#pragma unroll
    for (int r = 0; r < RQ; ++r) d[r] = 0.f;
#pragma unroll
    for (int kk = 0; kk < 16; ++kk) {
      float4 kv = kp[kk];
#pragma unroll
      for (int r = 0; r < RQ; ++r) {
        d[r] += kv.x * qs[r][kk * 4 + 0];
        d[r] += kv.y * qs[r][kk * 4 + 1];
        d[r] += kv.z * qs[r][kk * 4 + 2];
        d[r] += kv.w * qs[r][kk * 4 + 3];
      }
    }
#pragma unroll
    for (int r = 0; r < RQ; ++r) ex[si][r] = __expf(d[r] * 0.125f);
  }

  // row sums: thread partial -> wave shuffle -> cross-wave via LDS
  float part[RQ];
#pragma unroll
  for (int r = 0; r < RQ; ++r) {
    part[r] = 0.f;
#pragma unroll
    for (int si = 0; si < 8; ++si) part[r] += ex[si][r];
  }
#pragma unroll
  for (int r = 0; r < RQ; ++r)
    for (int off = 32; off >= 1; off >>= 1)
      part[r] += __shfl_down(part[r], off);

  __shared__ float wsum[4][RQ];
  int lane = t & 63, w = t >> 6;
  if (lane == 0) {
#pragma unroll
    for (int r = 0; r < RQ; ++r) wsum[w][r] = part[r];
  }
  __syncthreads();
  float inv[RQ];
#pragma unroll
  for (int r = 0; r < RQ; ++r)
    inv[r] = 1.f / (wsum[0][r] + wsum[1][r] + wsum[2][r] + wsum[3][r]);

#pragma unroll
  for (int si = 0; si < 8; ++si) {
#pragma unroll
    for (int r = 0; r < RQ; ++r) {
      P[((size_t)hh * T_ + r0 + r) * T_ + si * 256 + t] =
          __float2bfloat16(ex[si][r] * inv[r]);
    }
  }
}

// ---------------- bf16 NT GEMM, 128x128 tile, MFMA ----------------
// C[r, c_col0 + z*c_zcol + c] = sum_k A[z][r,k] * BT[c,k]
// A: [M,K] row-major (lda), batched by a_zstride. BT: [N,K] row-major (ldb).
template <bool OUT_BF16>
__global__ __launch_bounds__(256) void gemm_bt_kernel(
    const bf16* __restrict__ A, long long a_zstride, int lda,
    const bf16* __restrict__ BT, int ldb,
    void* __restrict__ Cout, int ldc, long long c_col0, long long c_zcol,
    int K) {
  __shared__ bf16 lds_a[128 * 32];
  __shared__ bf16 lds_b[128 * 32];
  int t = threadIdx.x;
  int z = blockIdx.z;
  const bf16* Ab = A + (size_t)z * a_zstride;
  size_t row0 = (size_t)blockIdx.y * 128;
  size_t col0 = (size_t)blockIdx.x * 128;

  // staging addresses: thread t covers (row = t>>2, 8 k-elems at (t&3)*8)
  const bf16* ga = Ab + (row0 + (t >> 2)) * (size_t)lda + (t & 3) * 8;
  const bf16* gb = BT + (col0 + (t >> 2)) * (size_t)ldb + (t & 3) * 8;
  bf16* la = lds_a + t * 8;  // lane-contiguous 16B per lane (HW requirement)
  bf16* lb = lds_b + t * 8;

  f32x4 acc[4][4] = {};
  int lane = t & 63;
  int w = t >> 6;
  int wm = (w & 1) * 64, wn = (w >> 1) * 64;
  int lr = lane & 15, lq = lane >> 4;
  const int a_off0 = (wm + lr) * 32 + lq * 8;
  const int b_off0 = (wn + lr) * 32 + lq * 8;

  for (int k0 = 0; k0 < K; k0 += 32) {
    load_lds16(ga, la);
    load_lds16(ga + 64 * (size_t)lda, la + 64 * 32);
    load_lds16(gb, lb);
    load_lds16(gb + 64 * (size_t)ldb, lb + 64 * 32);
    ga += 32;
    gb += 32;
    __syncthreads();  // drains vmcnt (global_load_lds) + lgkm

    bf16x8 af[4], bfr[4];
#pragma unroll
    for (int i = 0; i < 4; ++i)
      af[i] = *(const bf16x8*)&lds_a[a_off0 + i * 16 * 32];
#pragma unroll
    for (int j = 0; j < 4; ++j)
      bfr[j] = *(const bf16x8*)&lds_b[b_off0 + j * 16 * 32];
#pragma unroll
    for (int i = 0; i < 4; ++i)
#pragma unroll
      for (int j = 0; j < 4; ++j)
        acc[i][j] =
            __builtin_amdgcn_mfma_f32_16x16x32_bf16(af[i], bfr[j], acc[i][j], 0, 0, 0);
    __syncthreads();
  }

  // epilogue: C/D layout col=lane&15, row=(lane>>4)*4+reg (m89/m91 verified)
  size_t ccol = (size_t)c_col0 + (size_t)z * c_zcol + col0;
#pragma unroll
  for (int i = 0; i < 4; ++i) {
    size_t r = row0 + wm + i * 16 + lq * 4;
#pragma unroll
    for (int j = 0; j < 4; ++j) {
      size_t c = ccol + wn + j * 16 + lr;
#pragma unroll
      for (int reg = 0; reg < 4; ++reg) {
        float v = acc[i][j][reg];
        if (OUT_BF16)
          ((bf16*)Cout)[(r + reg) * (size_t)ldc + c] = __float2bfloat16(v);
        else
          ((float*)Cout)[(r + reg) * (size_t)ldc + c] = v;
      }
    }
  }
}

extern "C" void kernel_launch(void* const* d_in, const int* in_sizes, int n_in,
                              void* d_out, int out_size, void* d_ws,
                              size_t ws_size, hipStream_t stream) {
  const float* x = (const float*)d_in[0];    // [B, T, C] fp32
  const float* wgt = (const float*)d_in[1];  // [D, E] fp32
  float* out = (float*)d_out;                // [B, T, E] fp32

  // ws layout (bf16 elements)
  bf16* xbT = (bf16*)d_ws;                        // [B][C][T]   8 MB
  bf16* wbT = xbT + (size_t)B_ * C_ * T_;         // [E][D]     32 MB
  bf16* Obuf = wbT + (size_t)E_ * D_;             // [B*T][D]  128 MB
  bf16* P = Obuf + (size_t)B_ * T_ * D_;          // [Hs][T][T] slab

  // transposes + casts
  transpose_cast_kernel<<<dim3(C_ / 32, T_ / 32, B_), dim3(32, 8), 0, stream>>>(
      x, xbT, T_, C_);
  transpose_cast_kernel<<<dim3(E_ / 32, D_ / 32, 1), dim3(32, 8), 0, stream>>>(
      wgt, wbT, D_, E_);

  // pick head-slab size so P fits in remaining ws
  size_t fixed_bytes =
      ((size_t)B_ * C_ * T_ + (size_t)E_ * D_ + (size_t)B_ * T_ * D_) * 2;
  int Hs = 16;
  while (Hs > 1 && fixed_bytes + (size_t)Hs * T_ * T_ * 2 > ws_size) Hs >>= 1;

  for (int b = 0; b < B_; ++b) {
    const float* xb = x + (size_t)b * T_ * C_;
    for (int h0 = 0; h0 < H_; h0 += Hs) {
      scores_softmax_kernel<<<dim3(T_ / 8, Hs), 256, 0, stream>>>(xb, P, h0);
      // O[b][t][h*C + c] = sum_s P[h][t][s] * xbT[b][c][s]
      gemm_bt_kernel<true><<<dim3(C_ / 128, T_ / 128, Hs), 256, 0, stream>>>(
          P, (long long)T_ * T_, T_, xbT + (size_t)b * C_ * T_, T_,
          (void*)(Obuf + (size_t)b * T_ * D_), D_, (long long)h0 * C_,
          (long long)C_, T_);
    }
  }
  // out = O @ W   via  BT = W^T
  gemm_bt_kernel<false><<<dim3(E_ / 128, (B_ * T_) / 128, 1), 256, 0, stream>>>(
      Obuf, 0LL, D_, wbT, D_, (void*)out, E_, 0LL, 0LL, D_);
}

// Round 2
// 1086.129 us; speedup vs baseline: 2.3863x; 2.3863x over previous
//
#include <hip/hip_runtime.h>
#include <hip/hip_bf16.h>

// ShardAttention R2: all three matmul phases on MFMA.
//   xbT[b][c][t] bf16, wbT[e][k] bf16, xh[b][h][t][64] bf16
//   scores GEMM (K=64): P_unnorm = exp(xh xh^T / 8) bf16   [Hs][T][T]
//   rowsum: l[h][t] = sum_s P_unnorm (fp32)
//   PV GEMM (K=2048): O[b][t][h*C+c] = (P @ xbT^T) * 1/l   bf16
//   proj GEMM split-K x8 (K=2048 each): out += O @ W  (fp32 atomicAdd,
//   d_out zeroed via hipMemsetAsync)   -- fixes 1-block/CU latency stall.

typedef __hip_bfloat16 bf16;
typedef __bf16 bf16x8 __attribute__((ext_vector_type(8)));
typedef float f32x4 __attribute__((ext_vector_type(4)));

#define B_ 2
#define T_ 2048
#define C_ 1024
#define H_ 16
#define D_ 16384
#define E_ 1024

__device__ __forceinline__ void load_lds16(const void* g, void* l) {
  __builtin_amdgcn_global_load_lds(
      (const __attribute__((address_space(1))) void*)g,
      (__attribute__((address_space(3))) void*)l, 16, 0, 0);
}

// ---------------- transpose + fp32->bf16 cast ----------------
__global__ __launch_bounds__(256) void transpose_cast_kernel(
    const float* __restrict__ in, bf16* __restrict__ out, int rows, int cols) {
  __shared__ float tile[32][33];
  size_t zoff = (size_t)blockIdx.z * rows * cols;
  int c0 = blockIdx.x * 32, r0 = blockIdx.y * 32;
  int tx = threadIdx.x, ty = threadIdx.y;
  for (int i = ty; i < 32; i += 8)
    tile[i][tx] = in[zoff + (size_t)(r0 + i) * cols + c0 + tx];
  __syncthreads();
  for (int i = ty; i < 32; i += 8)
    out[zoff + (size_t)(c0 + i) * rows + r0 + tx] = __float2bfloat16(tile[tx][i]);
}

// ---------------- x -> per-head bf16 [b][h][t][64] ----------------
__global__ __launch_bounds__(256) void xh_cast_kernel(
    const float* __restrict__ x, bf16* __restrict__ xh) {
  int bt = blockIdx.x;  // b*T + t
  int b = bt >> 11, t = bt & (T_ - 1);
  float4 v = ((const float4*)(x + (size_t)bt * C_))[threadIdx.x];
  int c = threadIdx.x * 4;
  int h = c >> 6, k = c & 63;
  bf16* o = xh + ((size_t)(b * H_ + h) * T_ + t) * 64 + k;
  o[0] = __float2bfloat16(v.x);
  o[1] = __float2bfloat16(v.y);
  o[2] = __float2bfloat16(v.z);
  o[3] = __float2bfloat16(v.w);
}

// ---------------- rowsum of bf16 matrix (fp32) ----------------
__global__ __launch_bounds__(256) void rowsum_kernel(
    const bf16* __restrict__ P, float* __restrict__ l) {
  int row = blockIdx.x * 4 + (threadIdx.x >> 6);
  int lane = threadIdx.x & 63;
  const bf16* pr = P + (size_t)row * T_;
  float acc = 0.f;
#pragma unroll
  for (int j = 0; j < 4; ++j) {
    bf16x8 v = *(const bf16x8*)(pr + (lane + j * 64) * 8);
#pragma unroll
    for (int k = 0; k < 8; ++k) acc += (float)v[k];
  }
  for (int off = 32; off >= 1; off >>= 1) acc += __shfl_down(acc, off);
  if (lane == 0) l[row] = acc;
}

// ---------------- bf16 NT GEMM, 128x128 tile, MFMA ----------------
// C[z*c_zflat + r*ldc + c] (op) sum_k A[z][r,k] * BT[z][c,k]
// MODE 0: store f32   MODE 2: store bf16(exp(v/8))
// MODE 3: store bf16(v / l[z*lzs + r])   MODE 4: atomicAdd f32
template <int MODE>
__global__ __launch_bounds__(256) void gemm_bt_kernel(
    const bf16* __restrict__ A, long long a_zstride, int lda,
    const bf16* __restrict__ BT, long long b_zstride, int ldb,
    void* __restrict__ Cout, int ldc, long long c_zflat,
    const float* __restrict__ lsum, int lzs, int K) {
  __shared__ bf16 lds_a[128 * 32];
  __shared__ bf16 lds_b[128 * 32];
  int t = threadIdx.x;
  int z = blockIdx.z;
  const bf16* Ab = A + (size_t)z * a_zstride;
  const bf16* Bb = BT + (size_t)z * b_zstride;
  size_t row0 = (size_t)blockIdx.y * 128;
  size_t col0 = (size_t)blockIdx.x * 128;

  const bf16* ga = Ab + (row0 + (t >> 2)) * (size_t)lda + (t & 3) * 8;
  const bf16* gb = Bb + (col0 + (t >> 2)) * (size_t)ldb + (t & 3) * 8;
  bf16* la = lds_a + t * 8;
  bf16* lb = lds_b + t * 8;

  f32x4 acc[4][4] = {};
  int lane = t & 63;
  int w = t >> 6;
  int wm = (w & 1) * 64, wn = (w >> 1) * 64;
  int lr = lane & 15, lq = lane >> 4;
  const int a_off0 = (wm + lr) * 32 + lq * 8;
  const int b_off0 = (wn + lr) * 32 + lq * 8;

  for (int k0 = 0; k0 < K; k0 += 32) {
    load_lds16(ga, la);
    load_lds16(ga + 64 * (size_t)lda, la + 64 * 32);
    load_lds16(gb, lb);
    load_lds16(gb + 64 * (size_t)ldb, lb + 64 * 32);
    ga += 32;
    gb += 32;
    __syncthreads();

    bf16x8 af[4], bfr[4];
#pragma unroll
    for (int i = 0; i < 4; ++i)
      af[i] = *(const bf16x8*)&lds_a[a_off0 + i * 16 * 32];
#pragma unroll
    for (int j = 0; j < 4; ++j)
      bfr[j] = *(const bf16x8*)&lds_b[b_off0 + j * 16 * 32];
#pragma unroll
    for (int i = 0; i < 4; ++i)
#pragma unroll
      for (int j = 0; j < 4; ++j)
        acc[i][j] = __builtin_amdgcn_mfma_f32_16x16x32_bf16(af[i], bfr[j],
                                                            acc[i][j], 0, 0, 0);
    __syncthreads();
  }

  // epilogue: C/D layout col=lane&15, row=(lane>>4)*4+reg (m89/m91 verified)
  size_t cbase = (size_t)z * c_zflat + col0;
#pragma unroll
  for (int i = 0; i < 4; ++i) {
    size_t r = row0 + wm + i * 16 + lq * 4;
    float4 inv4 = make_float4(1.f, 1.f, 1.f, 1.f);
    if (MODE == 3) {
      float4 lv = *(const float4*)&lsum[(size_t)z * lzs + r];
      inv4 = make_float4(1.f / lv.x, 1.f / lv.y, 1.f / lv.z, 1.f / lv.w);
    }
#pragma unroll
    for (int j = 0; j < 4; ++j) {
      size_t c = cbase + wn + j * 16 + lr;
#pragma unroll
      for (int reg = 0; reg < 4; ++reg) {
        float v = acc[i][j][reg];
        size_t idx = (r + reg) * (size_t)ldc + c;
        if (MODE == 0) {
          ((float*)Cout)[idx] = v;
        } else if (MODE == 2) {
          ((bf16*)Cout)[idx] = __float2bfloat16(__expf(v * 0.125f));
        } else if (MODE == 3) {
          float iv = reg == 0 ? inv4.x : reg == 1 ? inv4.y : reg == 2 ? inv4.z : inv4.w;
          ((bf16*)Cout)[idx] = __float2bfloat16(v * iv);
        } else {
          atomicAdd(((float*)Cout) + idx, v);
        }
      }
    }
  }
}

extern "C" void kernel_launch(void* const* d_in, const int* in_sizes, int n_in,
                              void* d_out, int out_size, void* d_ws,
                              size_t ws_size, hipStream_t stream) {
  const float* x = (const float*)d_in[0];    // [B, T, C] fp32
  const float* wgt = (const float*)d_in[1];  // [D, E] fp32
  float* out = (float*)d_out;                // [B, T, E] fp32

  // ws layout (bf16 elements unless noted)
  bf16* xbT = (bf16*)d_ws;                        // [B][C][T]    8 MB
  bf16* wbT = xbT + (size_t)B_ * C_ * T_;         // [E][D]      32 MB
  bf16* xh = wbT + (size_t)E_ * D_;               // [B][H][T][64] 8 MB
  bf16* Obuf = xh + (size_t)B_ * H_ * T_ * 64;    // [B*T][D]   128 MB
  float* lsum = (float*)(Obuf + (size_t)B_ * T_ * D_);  // [16][T] 128 KB
  bf16* P = (bf16*)(lsum + (size_t)16 * T_);      // [Hs][T][T] slab

  hipMemsetAsync(d_out, 0, (size_t)out_size * sizeof(float), stream);

  transpose_cast_kernel<<<dim3(C_ / 32, T_ / 32, B_), dim3(32, 8), 0, stream>>>(
      x, xbT, T_, C_);
  transpose_cast_kernel<<<dim3(E_ / 32, D_ / 32, 1), dim3(32, 8), 0, stream>>>(
      wgt, wbT, D_, E_);
  xh_cast_kernel<<<B_ * T_, 256, 0, stream>>>(x, xh);

  // head-slab size so P fits in ws
  size_t fixed_bytes = ((size_t)B_ * C_ * T_ + (size_t)E_ * D_ +
                        (size_t)B_ * H_ * T_ * 64 + (size_t)B_ * T_ * D_) * 2 +
                       (size_t)16 * T_ * 4;
  int Hs = 16;
  while (Hs > 1 && fixed_bytes + (size_t)Hs * T_ * T_ * 2 > ws_size) Hs >>= 1;

  for (int b = 0; b < B_; ++b) {
    for (int h0 = 0; h0 < H_; h0 += Hs) {
      const bf16* xhb = xh + (size_t)(b * H_ + h0) * T_ * 64;
      // P_unnorm[z][t][s] = exp((xh_t . xh_s)/8), z in slab
      gemm_bt_kernel<2><<<dim3(T_ / 128, T_ / 128, Hs), 256, 0, stream>>>(
          xhb, (long long)T_ * 64, 64, xhb, (long long)T_ * 64, 64, (void*)P,
          T_, (long long)T_ * T_, nullptr, 0, 64);
      rowsum_kernel<<<Hs * T_ / 4, 256, 0, stream>>>(P, lsum);
      // O[b][t][(h0+z)*64.. ] wait: per-head channel block is C_ wide
      gemm_bt_kernel<3><<<dim3(C_ / 128, T_ / 128, Hs), 256, 0, stream>>>(
          P, (long long)T_ * T_, T_, xbT + (size_t)b * C_ * T_, 0LL, T_,
          (void*)(Obuf + (size_t)b * T_ * D_ + (size_t)h0 * C_), D_,
          (long long)C_, lsum, T_, T_);
    }
  }
  // out += O @ W, split-K x8 (z = k-chunk of 2048)
  gemm_bt_kernel<4><<<dim3(E_ / 128, (B_ * T_) / 128, 8), 256, 0, stream>>>(
      Obuf, 2048LL, D_, wbT, 2048LL, D_, (void*)out, E_, 0LL, nullptr, 0,
      2048);
}

// Round 3
// 928.623 us; speedup vs baseline: 2.7910x; 1.1696x over previous
//
#include <hip/hip_runtime.h>
#include <hip/hip_bf16.h>

// ShardAttention R3:
//   scores GEMM (K=64): P_unnorm = exp(xh xh^T / 8) bf16, epilogue fuses
//                       row-sum (shuffle-reduce + sparse atomicAdd -> lsum)
//   PV GEMM (K=2048):   O = (P @ xbT^T) * 1/l  bf16   [XCD-swizzled]
//   proj GEMM split-K x4 -> fp32 partials (plain stores) [XCD-swizzled]
//   reduce: out = sum_z partials
// XCD swizzle: all col-blocks sharing an A-strip land on one XCD's L2
// (assumes XCD = linear_block_id % 8, perf heuristic only).

typedef __hip_bfloat16 bf16;
typedef __bf16 bf16x8 __attribute__((ext_vector_type(8)));
typedef float f32x4 __attribute__((ext_vector_type(4)));

#define B_ 2
#define T_ 2048
#define C_ 1024
#define H_ 16
#define D_ 16384
#define E_ 1024
#define KZ_ 4  // proj split-K chunks

__device__ __forceinline__ void load_lds16(const void* g, void* l) {
  __builtin_amdgcn_global_load_lds(
      (const __attribute__((address_space(1))) void*)g,
      (__attribute__((address_space(3))) void*)l, 16, 0, 0);
}

// ---------------- transpose + fp32->bf16 cast ----------------
__global__ __launch_bounds__(256) void transpose_cast_kernel(
    const float* __restrict__ in, bf16* __restrict__ out, int rows, int cols) {
  __shared__ float tile[32][33];
  size_t zoff = (size_t)blockIdx.z * rows * cols;
  int c0 = blockIdx.x * 32, r0 = blockIdx.y * 32;
  int tx = threadIdx.x, ty = threadIdx.y;
  for (int i = ty; i < 32; i += 8)
    tile[i][tx] = in[zoff + (size_t)(r0 + i) * cols + c0 + tx];
  __syncthreads();
  for (int i = ty; i < 32; i += 8)
    out[zoff + (size_t)(c0 + i) * rows + r0 + tx] = __float2bfloat16(tile[tx][i]);
}

// ---------------- x -> per-head bf16 [b][h][t][64] ----------------
__global__ __launch_bounds__(256) void xh_cast_kernel(
    const float* __restrict__ x, bf16* __restrict__ xh) {
  int bt = blockIdx.x;
  int b = bt >> 11, t = bt & (T_ - 1);
  float4 v = ((const float4*)(x + (size_t)bt * C_))[threadIdx.x];
  int c = threadIdx.x * 4;
  int h = c >> 6, k = c & 63;
  bf16* o = xh + ((size_t)(b * H_ + h) * T_ + t) * 64 + k;
  o[0] = __float2bfloat16(v.x);
  o[1] = __float2bfloat16(v.y);
  o[2] = __float2bfloat16(v.z);
  o[3] = __float2bfloat16(v.w);
}

// ---------------- reduce KZ_ fp32 partials -> out ----------------
__global__ __launch_bounds__(256) void reduce_kernel(
    const float* __restrict__ p, float* __restrict__ out, int n4) {
  int i = blockIdx.x * 256 + threadIdx.x;
  if (i >= n4) return;
  float4 a = ((const float4*)p)[i];
#pragma unroll
  for (int z = 1; z < KZ_; ++z) {
    float4 b = ((const float4*)(p + (size_t)z * n4 * 4))[i];
    a.x += b.x; a.y += b.y; a.z += b.z; a.w += b.w;
  }
  ((float4*)out)[i] = a;
}

// ---------------- bf16 NT GEMM, 128x128 tile, MFMA ----------------
// MODE 0: store f32 partial
// MODE 2: store bf16(exp(v/8)) + fused row-sum atomicAdd into lsum
// MODE 3: store bf16(v / lsum[z*lzs + r])
template <int MODE, int SWZ>
__global__ __launch_bounds__(256) void gemm_bt_kernel(
    const bf16* __restrict__ A, long long a_zstride, int lda,
    const bf16* __restrict__ BT, long long b_zstride, int ldb,
    void* __restrict__ Cout, int ldc, long long c_zflat,
    float* __restrict__ lsum, int lzs, int K) {
  __shared__ bf16 lds_a[128 * 32];
  __shared__ bf16 lds_b[128 * 32];
  int t = threadIdx.x;

  int bx = blockIdx.x, by = blockIdx.y, bz = blockIdx.z;
  if (SWZ) {
    int gx = gridDim.x, gy = gridDim.y, gz = gridDim.z;
    int S = gy * gz, nb = gx * S;
    if (((S & 7) == 0) && ((nb & 7) == 0)) {
      int L = bx + gx * (by + gy * bz);
      int xcd = L & 7, m = L >> 3, spx = S >> 3;
      int col = m % gx, sl = m / gx;
      int strip = xcd * spx + sl;
      bx = col; by = strip % gy; bz = strip / gy;
    }
  }

  const bf16* Ab = A + (size_t)bz * a_zstride;
  const bf16* Bb = BT + (size_t)bz * b_zstride;
  size_t row0 = (size_t)by * 128;
  size_t col0 = (size_t)bx * 128;

  const bf16* ga = Ab + (row0 + (t >> 2)) * (size_t)lda + (t & 3) * 8;
  const bf16* gb = Bb + (col0 + (t >> 2)) * (size_t)ldb + (t & 3) * 8;
  bf16* la = lds_a + t * 8;
  bf16* lb = lds_b + t * 8;

  f32x4 acc[4][4] = {};
  int lane = t & 63;
  int w = t >> 6;
  int wm = (w & 1) * 64, wn = (w >> 1) * 64;
  int lr = lane & 15, lq = lane >> 4;
  const int a_off0 = (wm + lr) * 32 + lq * 8;
  const int b_off0 = (wn + lr) * 32 + lq * 8;

  for (int k0 = 0; k0 < K; k0 += 32) {
    load_lds16(ga, la);
    load_lds16(ga + 64 * (size_t)lda, la + 64 * 32);
    load_lds16(gb, lb);
    load_lds16(gb + 64 * (size_t)ldb, lb + 64 * 32);
    ga += 32;
    gb += 32;
    __syncthreads();

    bf16x8 af[4], bfr[4];
#pragma unroll
    for (int i = 0; i < 4; ++i)
      af[i] = *(const bf16x8*)&lds_a[a_off0 + i * 16 * 32];
#pragma unroll
    for (int j = 0; j < 4; ++j)
      bfr[j] = *(const bf16x8*)&lds_b[b_off0 + j * 16 * 32];
#pragma unroll
    for (int i = 0; i < 4; ++i)
#pragma unroll
      for (int j = 0; j < 4; ++j)
        acc[i][j] = __builtin_amdgcn_mfma_f32_16x16x32_bf16(af[i], bfr[j],
                                                            acc[i][j], 0, 0, 0);
    __syncthreads();
  }

  // epilogue: C/D layout col=lane&15, row=(lane>>4)*4+reg (m89/m91 verified)
  size_t cbase = (size_t)bz * c_zflat + col0;
  float rs[4][4];  // MODE 2 row-sum partials [i][reg]
#pragma unroll
  for (int i = 0; i < 4; ++i) {
    size_t r = row0 + wm + i * 16 + lq * 4;
    float4 inv4 = make_float4(1.f, 1.f, 1.f, 1.f);
    if (MODE == 3) {
      float4 lv = *(const float4*)&lsum[(size_t)bz * lzs + r];
      inv4 = make_float4(1.f / lv.x, 1.f / lv.y, 1.f / lv.z, 1.f / lv.w);
    }
    if (MODE == 2) {
#pragma unroll
      for (int reg = 0; reg < 4; ++reg) rs[i][reg] = 0.f;
    }
#pragma unroll
    for (int j = 0; j < 4; ++j) {
      size_t c = cbase + wn + j * 16 + lr;
#pragma unroll
      for (int reg = 0; reg < 4; ++reg) {
        float v = acc[i][j][reg];
        size_t idx = (r + reg) * (size_t)ldc + c;
        if (MODE == 0) {
          ((float*)Cout)[idx] = v;
        } else if (MODE == 2) {
          float e = __expf(v * 0.125f);
          rs[i][reg] += e;
          ((bf16*)Cout)[idx] = __float2bfloat16(e);
        } else if (MODE == 3) {
          float iv = reg == 0 ? inv4.x : reg == 1 ? inv4.y : reg == 2 ? inv4.z
                                                                      : inv4.w;
          ((bf16*)Cout)[idx] = __float2bfloat16(v * iv);
        }
      }
    }
  }
  if (MODE == 2) {
    // reduce across the 16 lr-lanes (lane bits 0..3), then 1 atomic per row
#pragma unroll
    for (int i = 0; i < 4; ++i)
#pragma unroll
      for (int reg = 0; reg < 4; ++reg) {
#pragma unroll
        for (int off = 1; off < 16; off <<= 1)
          rs[i][reg] += __shfl_xor(rs[i][reg], off);
      }
    if (lr == 0) {
#pragma unroll
      for (int i = 0; i < 4; ++i) {
        size_t r = row0 + wm + i * 16 + lq * 4;
#pragma unroll
        for (int reg = 0; reg < 4; ++reg)
          atomicAdd(&lsum[(size_t)bz * T_ + r + reg], rs[i][reg]);
      }
    }
  }
}

extern "C" void kernel_launch(void* const* d_in, const int* in_sizes, int n_in,
                              void* d_out, int out_size, void* d_ws,
                              size_t ws_size, hipStream_t stream) {
  const float* x = (const float*)d_in[0];    // [B, T, C] fp32
  const float* wgt = (const float*)d_in[1];  // [D, E] fp32
  float* out = (float*)d_out;                // [B, T, E] fp32

  // ws layout
  bf16* xbT = (bf16*)d_ws;                        // [B][C][T]    8 MB
  bf16* wbT = xbT + (size_t)B_ * C_ * T_;         // [E][D]      32 MB
  bf16* xh = wbT + (size_t)E_ * D_;               // [B][H][T][64] 8 MB
  bf16* Obuf = xh + (size_t)B_ * H_ * T_ * 64;    // [B*T][D]   128 MB
  float* lsum = (float*)(Obuf + (size_t)B_ * T_ * D_);  // [16][T] 128 KB
  bf16* P = (bf16*)(lsum + (size_t)16 * T_);      // [Hs][T][T] slab
  float* partials = (float*)P;                    // reuse slab for proj (64 MB)

  transpose_cast_kernel<<<dim3(C_ / 32, T_ / 32, B_), dim3(32, 8), 0, stream>>>(
      x, xbT, T_, C_);
  transpose_cast_kernel<<<dim3(E_ / 32, D_ / 32, 1), dim3(32, 8), 0, stream>>>(
      wgt, wbT, D_, E_);
  xh_cast_kernel<<<B_ * T_, 256, 0, stream>>>(x, xh);

  size_t fixed_bytes = ((size_t)B_ * C_ * T_ + (size_t)E_ * D_ +
                        (size_t)B_ * H_ * T_ * 64 + (size_t)B_ * T_ * D_) * 2 +
                       (size_t)16 * T_ * 4;
  int Hs = 16;
  while (Hs > 1 && fixed_bytes + (size_t)Hs * T_ * T_ * 2 > ws_size) Hs >>= 1;

  for (int b = 0; b < B_; ++b) {
    for (int h0 = 0; h0 < H_; h0 += Hs) {
      const bf16* xhb = xh + (size_t)(b * H_ + h0) * T_ * 64;
      hipMemsetAsync(lsum, 0, (size_t)Hs * T_ * sizeof(float), stream);
      // P_unnorm + fused rowsum
      gemm_bt_kernel<2, 0><<<dim3(T_ / 128, T_ / 128, Hs), 256, 0, stream>>>(
          xhb, (long long)T_ * 64, 64, xhb, (long long)T_ * 64, 64, (void*)P,
          T_, (long long)T_ * T_, lsum, T_, 64);
      // O = (P @ xbT^T) / l
      gemm_bt_kernel<3, 1><<<dim3(C_ / 128, T_ / 128, Hs), 256, 0, stream>>>(
          P, (long long)T_ * T_, T_, xbT + (size_t)b * C_ * T_, 0LL, T_,
          (void*)(Obuf + (size_t)b * T_ * D_ + (size_t)h0 * C_), D_,
          (long long)C_, lsum, T_, T_);
    }
  }
  // proj: partials[z] = O[:, z*4096:(z+1)*4096] @ W[z*4096:(z+1)*4096, :]
  gemm_bt_kernel<0, 1><<<dim3(E_ / 128, (B_ * T_) / 128, KZ_), 256, 0,
                         stream>>>(Obuf, (long long)(D_ / KZ_), D_, wbT,
                                   (long long)(D_ / KZ_), D_, (void*)partials,
                                   E_, (long long)B_ * T_ * E_, nullptr, 0,
                                   D_ / KZ_);
  reduce_kernel<<<(B_ * T_ * E_ / 4 + 255) / 256, 256, 0, stream>>>(
      partials, out, B_ * T_ * E_ / 4);
}

// Round 4
// 897.974 us; speedup vs baseline: 2.8863x; 1.0341x over previous
//
#include <hip/hip_runtime.h>
#include <hip/hip_bf16.h>

// ShardAttention R4:
//   scores: symmetric — only upper-triangle tiles (136 of 256), K=64 single
//           staging round, epilogue: exp -> direct store + mirrored (packed
//           8B) store, fused row-sum AND col-sum atomics into lsum.
//   PV / proj: BK=64 K-loop (32 KB LDS, half the barriers of R3).
//   proj split-K x4 -> fp32 partials + reduce.  XCD swizzle kept.

typedef __hip_bfloat16 bf16;
typedef __bf16 bf16x8 __attribute__((ext_vector_type(8)));
typedef float f32x4 __attribute__((ext_vector_type(4)));

#define B_ 2
#define T_ 2048
#define C_ 1024
#define H_ 16
#define D_ 16384
#define E_ 1024
#define KZ_ 4  // proj split-K chunks

__device__ __forceinline__ void load_lds16(const void* g, void* l) {
  __builtin_amdgcn_global_load_lds(
      (const __attribute__((address_space(1))) void*)g,
      (__attribute__((address_space(3))) void*)l, 16, 0, 0);
}

__device__ __forceinline__ unsigned pack2(float a, float b) {
  union { bf16 h[2]; unsigned u; } p;
  p.h[0] = __float2bfloat16(a);
  p.h[1] = __float2bfloat16(b);
  return p.u;
}

// ---------------- transpose + fp32->bf16 cast ----------------
__global__ __launch_bounds__(256) void transpose_cast_kernel(
    const float* __restrict__ in, bf16* __restrict__ out, int rows, int cols) {
  __shared__ float tile[32][33];
  size_t zoff = (size_t)blockIdx.z * rows * cols;
  int c0 = blockIdx.x * 32, r0 = blockIdx.y * 32;
  int tx = threadIdx.x, ty = threadIdx.y;
  for (int i = ty; i < 32; i += 8)
    tile[i][tx] = in[zoff + (size_t)(r0 + i) * cols + c0 + tx];
  __syncthreads();
  for (int i = ty; i < 32; i += 8)
    out[zoff + (size_t)(c0 + i) * rows + r0 + tx] = __float2bfloat16(tile[tx][i]);
}

// ---------------- x -> per-head bf16 [b][h][t][64] ----------------
__global__ __launch_bounds__(256) void xh_cast_kernel(
    const float* __restrict__ x, bf16* __restrict__ xh) {
  int bt = blockIdx.x;
  int b = bt >> 11, t = bt & (T_ - 1);
  float4 v = ((const float4*)(x + (size_t)bt * C_))[threadIdx.x];
  int c = threadIdx.x * 4;
  int h = c >> 6, k = c & 63;
  bf16* o = xh + ((size_t)(b * H_ + h) * T_ + t) * 64 + k;
  o[0] = __float2bfloat16(v.x);
  o[1] = __float2bfloat16(v.y);
  o[2] = __float2bfloat16(v.z);
  o[3] = __float2bfloat16(v.w);
}

// ---------------- reduce KZ_ fp32 partials -> out ----------------
__global__ __launch_bounds__(256) void reduce_kernel(
    const float* __restrict__ p, float* __restrict__ out, int n4) {
  int i = blockIdx.x * 256 + threadIdx.x;
  if (i >= n4) return;
  float4 a = ((const float4*)p)[i];
#pragma unroll
  for (int z = 1; z < KZ_; ++z) {
    float4 b = ((const float4*)(p + (size_t)z * n4 * 4))[i];
    a.x += b.x; a.y += b.y; a.z += b.z; a.w += b.w;
  }
  ((float4*)out)[i] = a;
}

// ---------------- scores: symmetric tiles, K=64, exp + sums ----------------
// grid (136, Hs). Tile (i,j), i<=j, of one head's 2048x2048 P_unnorm.
__global__ __launch_bounds__(256) void scores_kernel(
    const bf16* __restrict__ xh,  // [Hs][T][64]
    bf16* __restrict__ P,         // [Hs][T][T]
    float* __restrict__ lsum) {   // [Hs][T], pre-zeroed
  int L = blockIdx.x;
  int z = blockIdx.y;
  int ti = 0, rem = L;
  while (rem >= H_ - ti) { rem -= H_ - ti; ++ti; }
  int tj = ti + rem;  // ti <= tj

  const bf16* A = xh + (size_t)z * T_ * 64;
  bf16* Pz = P + (size_t)z * T_ * T_;
  size_t row0 = (size_t)ti * 128, col0 = (size_t)tj * 128;

  __shared__ bf16 lds_a[128 * 64];
  __shared__ bf16 lds_b[128 * 64];
  int t = threadIdx.x;

  // stage full K=64 strips (row-major [128][64])
  const bf16* ga = A + (row0 + (t >> 3)) * 64 + (t & 7) * 8;
  const bf16* gb = A + (col0 + (t >> 3)) * 64 + (t & 7) * 8;
#pragma unroll
  for (int q = 0; q < 4; ++q) {
    load_lds16(ga + q * 32 * 64, lds_a + t * 8 + q * 2048);
    load_lds16(gb + q * 32 * 64, lds_b + t * 8 + q * 2048);
  }
  __syncthreads();

  int lane = t & 63, w = t >> 6;
  int wm = (w & 1) * 64, wn = (w >> 1) * 64;
  int lr = lane & 15, lq = lane >> 4;
  const int a_off = (wm + lr) * 64 + lq * 8;
  const int b_off = (wn + lr) * 64 + lq * 8;

  f32x4 acc[4][4] = {};
#pragma unroll
  for (int kh = 0; kh < 2; ++kh) {
    bf16x8 af[4], bfr[4];
#pragma unroll
    for (int i = 0; i < 4; ++i)
      af[i] = *(const bf16x8*)&lds_a[a_off + kh * 32 + i * 16 * 64];
#pragma unroll
    for (int j = 0; j < 4; ++j)
      bfr[j] = *(const bf16x8*)&lds_b[b_off + kh * 32 + j * 16 * 64];
#pragma unroll
    for (int i = 0; i < 4; ++i)
#pragma unroll
      for (int j = 0; j < 4; ++j)
        acc[i][j] = __builtin_amdgcn_mfma_f32_16x16x32_bf16(af[i], bfr[j],
                                                            acc[i][j], 0, 0, 0);
  }

  // epilogue: e = exp(v/8); direct + mirrored stores; row & col sums
  float rs[4][4];  // row-sum partial [i2][reg]
  float cs[4];     // col-sum partial [j2]
#pragma unroll
  for (int i2 = 0; i2 < 4; ++i2)
#pragma unroll
    for (int reg = 0; reg < 4; ++reg) rs[i2][reg] = 0.f;
#pragma unroll
  for (int j2 = 0; j2 < 4; ++j2) cs[j2] = 0.f;

#pragma unroll
  for (int i2 = 0; i2 < 4; ++i2) {
    size_t rb = row0 + wm + i2 * 16 + lq * 4;
#pragma unroll
    for (int j2 = 0; j2 < 4; ++j2) {
      size_t c = col0 + wn + j2 * 16 + lr;
      float e[4];
#pragma unroll
      for (int reg = 0; reg < 4; ++reg) {
        e[reg] = __expf(acc[i2][j2][reg] * 0.125f);
        rs[i2][reg] += e[reg];
        cs[j2] += e[reg];
        Pz[(rb + reg) * T_ + c] = __float2bfloat16(e[reg]);
      }
      // mirror: P[c][rb..rb+3], 8B packed
      uint2 mv;
      mv.x = pack2(e[0], e[1]);
      mv.y = pack2(e[2], e[3]);
      *(uint2*)&Pz[c * T_ + rb] = mv;
    }
  }

  // row sums: reduce over lr (lane bits 0..3), atomic by lr==0 lanes
#pragma unroll
  for (int i2 = 0; i2 < 4; ++i2)
#pragma unroll
    for (int reg = 0; reg < 4; ++reg) {
#pragma unroll
      for (int off = 1; off < 16; off <<= 1)
        rs[i2][reg] += __shfl_xor(rs[i2][reg], off);
    }
  if (lr == 0) {
#pragma unroll
    for (int i2 = 0; i2 < 4; ++i2) {
      size_t rb = row0 + wm + i2 * 16 + lq * 4;
#pragma unroll
      for (int reg = 0; reg < 4; ++reg)
        atomicAdd(&lsum[(size_t)z * T_ + rb + reg], rs[i2][reg]);
    }
  }
  // col sums (mirror rows): reduce over lq (lane bits 4..5), atomic lane<16
  if (ti != tj) {
#pragma unroll
    for (int j2 = 0; j2 < 4; ++j2) {
      cs[j2] += __shfl_xor(cs[j2], 16);
      cs[j2] += __shfl_xor(cs[j2], 32);
    }
    if (lq == 0) {
#pragma unroll
      for (int j2 = 0; j2 < 4; ++j2) {
        size_t c = col0 + wn + j2 * 16 + lr;
        atomicAdd(&lsum[(size_t)z * T_ + c], cs[j2]);
      }
    }
  }
}

// ---------------- bf16 NT GEMM, 128x128 tile, BK=64, MFMA ----------------
// MODE 0: store f32 partial   MODE 3: store bf16(v / lsum[bz*lzs + r])
template <int MODE, int SWZ>
__global__ __launch_bounds__(256) void gemm_bt_kernel(
    const bf16* __restrict__ A, long long a_zstride, int lda,
    const bf16* __restrict__ BT, long long b_zstride, int ldb,
    void* __restrict__ Cout, int ldc, long long c_zflat,
    const float* __restrict__ lsum, int lzs, int K) {
  __shared__ bf16 lds_a[128 * 64];
  __shared__ bf16 lds_b[128 * 64];
  int t = threadIdx.x;

  int bx = blockIdx.x, by = blockIdx.y, bz = blockIdx.z;
  if (SWZ) {
    int gx = gridDim.x, gy = gridDim.y, gz = gridDim.z;
    int S = gy * gz, nb = gx * S;
    if (((S & 7) == 0) && ((nb & 7) == 0)) {
      int L = bx + gx * (by + gy * bz);
      int xcd = L & 7, m = L >> 3, spx = S >> 3;
      int col = m % gx, sl = m / gx;
      int strip = xcd * spx + sl;
      bx = col; by = strip % gy; bz = strip / gy;
    }
  }

  const bf16* Ab = A + (size_t)bz * a_zstride;
  const bf16* Bb = BT + (size_t)bz * b_zstride;
  size_t row0 = (size_t)by * 128;
  size_t col0 = (size_t)bx * 128;

  // staging: thread t covers (row t>>3, 8 k-elems at (t&7)*8), 4 stages x 32 rows
  const bf16* ga = Ab + (row0 + (t >> 3)) * (size_t)lda + (t & 7) * 8;
  const bf16* gb = Bb + (col0 + (t >> 3)) * (size_t)ldb + (t & 7) * 8;
  bf16* la = lds_a + t * 8;
  bf16* lb = lds_b + t * 8;

  f32x4 acc[4][4] = {};
  int lane = t & 63;
  int w = t >> 6;
  int wm = (w & 1) * 64, wn = (w >> 1) * 64;
  int lr = lane & 15, lq = lane >> 4;
  const int a_off = (wm + lr) * 64 + lq * 8;
  const int b_off = (wn + lr) * 64 + lq * 8;

  for (int k0 = 0; k0 < K; k0 += 64) {
#pragma unroll
    for (int q = 0; q < 4; ++q) {
      load_lds16(ga + (size_t)q * 32 * lda, la + q * 2048);
      load_lds16(gb + (size_t)q * 32 * ldb, lb + q * 2048);
    }
    ga += 64;
    gb += 64;
    __syncthreads();

#pragma unroll
    for (int kh = 0; kh < 2; ++kh) {
      bf16x8 af[4], bfr[4];
#pragma unroll
      for (int i = 0; i < 4; ++i)
        af[i] = *(const bf16x8*)&lds_a[a_off + kh * 32 + i * 16 * 64];
#pragma unroll
      for (int j = 0; j < 4; ++j)
        bfr[j] = *(const bf16x8*)&lds_b[b_off + kh * 32 + j * 16 * 64];
#pragma unroll
      for (int i = 0; i < 4; ++i)
#pragma unroll
        for (int j = 0; j < 4; ++j)
          acc[i][j] = __builtin_amdgcn_mfma_f32_16x16x32_bf16(
              af[i], bfr[j], acc[i][j], 0, 0, 0);
    }
    __syncthreads();
  }

  // epilogue: C/D layout col=lane&15, row=(lane>>4)*4+reg (m89/m91 verified)
  size_t cbase = (size_t)bz * c_zflat + col0;
#pragma unroll
  for (int i = 0; i < 4; ++i) {
    size_t r = row0 + wm + i * 16 + lq * 4;
    float4 inv4 = make_float4(1.f, 1.f, 1.f, 1.f);
    if (MODE == 3) {
      float4 lv = *(const float4*)&lsum[(size_t)bz * lzs + r];
      inv4 = make_float4(1.f / lv.x, 1.f / lv.y, 1.f / lv.z, 1.f / lv.w);
    }
#pragma unroll
    for (int j = 0; j < 4; ++j) {
      size_t c = cbase + wn + j * 16 + lr;
#pragma unroll
      for (int reg = 0; reg < 4; ++reg) {
        float v = acc[i][j][reg];
        size_t idx = (r + reg) * (size_t)ldc + c;
        if (MODE == 0) {
          ((float*)Cout)[idx] = v;
        } else {
          float iv = reg == 0 ? inv4.x : reg == 1 ? inv4.y : reg == 2 ? inv4.z
                                                                      : inv4.w;
          ((bf16*)Cout)[idx] = __float2bfloat16(v * iv);
        }
      }
    }
  }
}

extern "C" void kernel_launch(void* const* d_in, const int* in_sizes, int n_in,
                              void* d_out, int out_size, void* d_ws,
                              size_t ws_size, hipStream_t stream) {
  const float* x = (const float*)d_in[0];    // [B, T, C] fp32
  const float* wgt = (const float*)d_in[1];  // [D, E] fp32
  float* out = (float*)d_out;                // [B, T, E] fp32

  // ws layout
  bf16* xbT = (bf16*)d_ws;                        // [B][C][T]    8 MB
  bf16* wbT = xbT + (size_t)B_ * C_ * T_;         // [E][D]      32 MB
  bf16* xh = wbT + (size_t)E_ * D_;               // [B][H][T][64] 8 MB
  bf16* Obuf = xh + (size_t)B_ * H_ * T_ * 64;    // [B*T][D]   128 MB
  float* lsum = (float*)(Obuf + (size_t)B_ * T_ * D_);  // [16][T] 128 KB
  bf16* P = (bf16*)(lsum + (size_t)16 * T_);      // [Hs][T][T] slab
  float* partials = (float*)P;                    // reuse slab for proj

  transpose_cast_kernel<<<dim3(C_ / 32, T_ / 32, B_), dim3(32, 8), 0, stream>>>(
      x, xbT, T_, C_);
  transpose_cast_kernel<<<dim3(E_ / 32, D_ / 32, 1), dim3(32, 8), 0, stream>>>(
      wgt, wbT, D_, E_);
  xh_cast_kernel<<<B_ * T_, 256, 0, stream>>>(x, xh);

  size_t fixed_bytes = ((size_t)B_ * C_ * T_ + (size_t)E_ * D_ +
                        (size_t)B_ * H_ * T_ * 64 + (size_t)B_ * T_ * D_) * 2 +
                       (size_t)16 * T_ * 4;
  int Hs = 16;
  while (Hs > 1 && fixed_bytes + (size_t)Hs * T_ * T_ * 2 > ws_size) Hs >>= 1;
  int ntri = Hs == 16 ? 136 : 136;  // triangular tiles for 16x16 grid
  (void)ntri;

  for (int b = 0; b < B_; ++b) {
    for (int h0 = 0; h0 < H_; h0 += Hs) {
      const bf16* xhb = xh + (size_t)(b * H_ + h0) * T_ * 64;
      hipMemsetAsync(lsum, 0, (size_t)Hs * T_ * sizeof(float), stream);
      scores_kernel<<<dim3(136, Hs), 256, 0, stream>>>(xhb, P, lsum);
      // O = (P @ xbT^T) / l
      gemm_bt_kernel<3, 1><<<dim3(C_ / 128, T_ / 128, Hs), 256, 0, stream>>>(
          P, (long long)T_ * T_, T_, xbT + (size_t)b * C_ * T_, 0LL, T_,
          (void*)(Obuf + (size_t)b * T_ * D_ + (size_t)h0 * C_), D_,
          (long long)C_, lsum, T_, T_);
    }
  }
  // proj: partials[z] = O[:, z*4096:(z+1)*4096] @ W[z*4096:(z+1)*4096, :]
  gemm_bt_kernel<0, 1><<<dim3(E_ / 128, (B_ * T_) / 128, KZ_), 256, 0,
                         stream>>>(Obuf, (long long)(D_ / KZ_), D_, wbT,
                                   (long long)(D_ / KZ_), D_, (void*)partials,
                                   E_, (long long)B_ * T_ * E_, nullptr, 0,
                                   D_ / KZ_);
  reduce_kernel<<<(B_ * T_ * E_ / 4 + 255) / 256, 256, 0, stream>>>(
      partials, out, B_ * T_ * E_ / 4);
}

// Round 5
// 755.632 us; speedup vs baseline: 3.4300x; 1.1884x over previous
//
#include <hip/hip_runtime.h>
#include <hip/hip_bf16.h>

// ShardAttention R5:
//   scores: symmetric tiles (136), K=64, fused exp + row/col sums, packed stores.
//   PV / proj: BK=32 (R3 layout), __launch_bounds__(256,4) to force 128
//   unified regs/wave -> 4 blocks/CU co-residency (barrier-drain overlap).
//   Epilogue: shfl_xor(1) column-pair packing -> dword stores (half the
//   store-issue). proj: split-K x8, bf16 partials + f32 reduce.

typedef __hip_bfloat16 bf16;
typedef __bf16 bf16x8 __attribute__((ext_vector_type(8)));
typedef float f32x4 __attribute__((ext_vector_type(4)));

#define B_ 2
#define T_ 2048
#define C_ 1024
#define H_ 16
#define D_ 16384
#define E_ 1024
#define KZ_ 8  // proj split-K chunks

__device__ __forceinline__ void load_lds16(const void* g, void* l) {
  __builtin_amdgcn_global_load_lds(
      (const __attribute__((address_space(1))) void*)g,
      (__attribute__((address_space(3))) void*)l, 16, 0, 0);
}

__device__ __forceinline__ unsigned pack2(float a, float b) {
  union { bf16 h[2]; unsigned u; } p;
  p.h[0] = __float2bfloat16(a);
  p.h[1] = __float2bfloat16(b);
  return p.u;
}

// ---------------- transpose + fp32->bf16 cast ----------------
__global__ __launch_bounds__(256) void transpose_cast_kernel(
    const float* __restrict__ in, bf16* __restrict__ out, int rows, int cols) {
  __shared__ float tile[32][33];
  size_t zoff = (size_t)blockIdx.z * rows * cols;
  int c0 = blockIdx.x * 32, r0 = blockIdx.y * 32;
  int tx = threadIdx.x, ty = threadIdx.y;
  for (int i = ty; i < 32; i += 8)
    tile[i][tx] = in[zoff + (size_t)(r0 + i) * cols + c0 + tx];
  __syncthreads();
  for (int i = ty; i < 32; i += 8)
    out[zoff + (size_t)(c0 + i) * rows + r0 + tx] = __float2bfloat16(tile[tx][i]);
}

// ---------------- x -> per-head bf16 [b][h][t][64] ----------------
__global__ __launch_bounds__(256) void xh_cast_kernel(
    const float* __restrict__ x, bf16* __restrict__ xh) {
  int bt = blockIdx.x;
  int b = bt >> 11, t = bt & (T_ - 1);
  float4 v = ((const float4*)(x + (size_t)bt * C_))[threadIdx.x];
  int c = threadIdx.x * 4;
  int h = c >> 6, k = c & 63;
  bf16* o = xh + ((size_t)(b * H_ + h) * T_ + t) * 64 + k;
  o[0] = __float2bfloat16(v.x);
  o[1] = __float2bfloat16(v.y);
  o[2] = __float2bfloat16(v.z);
  o[3] = __float2bfloat16(v.w);
}

// ---------------- reduce KZ_ bf16 partials -> f32 out ----------------
__global__ __launch_bounds__(256) void reduce_kernel(
    const bf16* __restrict__ p, float* __restrict__ out, int n8) {
  int i = blockIdx.x * 256 + threadIdx.x;
  if (i >= n8) return;
  float a[8] = {};
#pragma unroll
  for (int z = 0; z < KZ_; ++z) {
    bf16x8 v = ((const bf16x8*)(p + (size_t)z * n8 * 8))[i];
#pragma unroll
    for (int k = 0; k < 8; ++k) a[k] += (float)v[k];
  }
  float4 lo = make_float4(a[0], a[1], a[2], a[3]);
  float4 hi = make_float4(a[4], a[5], a[6], a[7]);
  ((float4*)out)[2 * i] = lo;
  ((float4*)out)[2 * i + 1] = hi;
}

// ---------------- scores: symmetric tiles, K=64, exp + sums ----------------
// grid (136, Hs). Tile (ti,tj), ti<=tj, of one head's 2048x2048 P_unnorm.
__global__ __launch_bounds__(256) void scores_kernel(
    const bf16* __restrict__ xh,  // [Hs][T][64]
    bf16* __restrict__ P,         // [Hs][T][T]
    float* __restrict__ lsum) {   // [Hs][T], pre-zeroed
  int L = blockIdx.x;
  int z = blockIdx.y;
  int ti = 0, rem = L;
  while (rem >= H_ - ti) { rem -= H_ - ti; ++ti; }
  int tj = ti + rem;  // ti <= tj

  const bf16* A = xh + (size_t)z * T_ * 64;
  bf16* Pz = P + (size_t)z * T_ * T_;
  size_t row0 = (size_t)ti * 128, col0 = (size_t)tj * 128;

  __shared__ bf16 lds_a[128 * 64];
  __shared__ bf16 lds_b[128 * 64];
  int t = threadIdx.x;

  const bf16* ga = A + (row0 + (t >> 3)) * 64 + (t & 7) * 8;
  const bf16* gb = A + (col0 + (t >> 3)) * 64 + (t & 7) * 8;
#pragma unroll
  for (int q = 0; q < 4; ++q) {
    load_lds16(ga + q * 32 * 64, lds_a + t * 8 + q * 2048);
    load_lds16(gb + q * 32 * 64, lds_b + t * 8 + q * 2048);
  }
  __syncthreads();

  int lane = t & 63, w = t >> 6;
  int wm = (w & 1) * 64, wn = (w >> 1) * 64;
  int lr = lane & 15, lq = lane >> 4;
  const int a_off = (wm + lr) * 64 + lq * 8;
  const int b_off = (wn + lr) * 64 + lq * 8;

  f32x4 acc[4][4] = {};
#pragma unroll
  for (int kh = 0; kh < 2; ++kh) {
    bf16x8 af[4], bfr[4];
#pragma unroll
    for (int i = 0; i < 4; ++i)
      af[i] = *(const bf16x8*)&lds_a[a_off + kh * 32 + i * 16 * 64];
#pragma unroll
    for (int j = 0; j < 4; ++j)
      bfr[j] = *(const bf16x8*)&lds_b[b_off + kh * 32 + j * 16 * 64];
#pragma unroll
    for (int i = 0; i < 4; ++i)
#pragma unroll
      for (int j = 0; j < 4; ++j)
        acc[i][j] = __builtin_amdgcn_mfma_f32_16x16x32_bf16(af[i], bfr[j],
                                                            acc[i][j], 0, 0, 0);
  }

  float rs[4][4];
  float cs[4];
#pragma unroll
  for (int i2 = 0; i2 < 4; ++i2)
#pragma unroll
    for (int reg = 0; reg < 4; ++reg) rs[i2][reg] = 0.f;
#pragma unroll
  for (int j2 = 0; j2 < 4; ++j2) cs[j2] = 0.f;

#pragma unroll
  for (int i2 = 0; i2 < 4; ++i2) {
    size_t rb = row0 + wm + i2 * 16 + lq * 4;
#pragma unroll
    for (int j2 = 0; j2 < 4; ++j2) {
      size_t c = col0 + wn + j2 * 16 + lr;
      float e[4];
#pragma unroll
      for (int reg = 0; reg < 4; ++reg) {
        e[reg] = __expf(acc[i2][j2][reg] * 0.125f);
        rs[i2][reg] += e[reg];
        cs[j2] += e[reg];
        float nb = __shfl_xor(e[reg], 1);
        if ((lr & 1) == 0)
          *(unsigned*)&Pz[(rb + reg) * T_ + c] = pack2(e[reg], nb);
      }
      // mirror: P[c][rb..rb+3], 8B packed
      uint2 mv;
      mv.x = pack2(e[0], e[1]);
      mv.y = pack2(e[2], e[3]);
      *(uint2*)&Pz[c * T_ + rb] = mv;
    }
  }

#pragma unroll
  for (int i2 = 0; i2 < 4; ++i2)
#pragma unroll
    for (int reg = 0; reg < 4; ++reg) {
#pragma unroll
      for (int off = 1; off < 16; off <<= 1)
        rs[i2][reg] += __shfl_xor(rs[i2][reg], off);
    }
  if (lr == 0) {
#pragma unroll
    for (int i2 = 0; i2 < 4; ++i2) {
      size_t rb = row0 + wm + i2 * 16 + lq * 4;
#pragma unroll
      for (int reg = 0; reg < 4; ++reg)
        atomicAdd(&lsum[(size_t)z * T_ + rb + reg], rs[i2][reg]);
    }
  }
  if (ti != tj) {
#pragma unroll
    for (int j2 = 0; j2 < 4; ++j2) {
      cs[j2] += __shfl_xor(cs[j2], 16);
      cs[j2] += __shfl_xor(cs[j2], 32);
    }
    if (lq == 0) {
#pragma unroll
      for (int j2 = 0; j2 < 4; ++j2) {
        size_t c = col0 + wn + j2 * 16 + lr;
        atomicAdd(&lsum[(size_t)z * T_ + c], cs[j2]);
      }
    }
  }
}

// ---------------- bf16 NT GEMM, 128x128 tile, BK=32, MFMA ----------------
// MODE 1: pack-store bf16   MODE 3: pack-store bf16(v / lsum[bz*lzs + r])
template <int MODE, int SWZ>
__global__ __launch_bounds__(256, 4) void gemm_bt_kernel(
    const bf16* __restrict__ A, long long a_zstride, int lda,
    const bf16* __restrict__ BT, long long b_zstride, int ldb,
    void* __restrict__ Cout, int ldc, long long c_zflat,
    const float* __restrict__ lsum, int lzs, int K) {
  __shared__ bf16 lds_a[128 * 32];
  __shared__ bf16 lds_b[128 * 32];
  int t = threadIdx.x;

  int bx = blockIdx.x, by = blockIdx.y, bz = blockIdx.z;
  if (SWZ) {
    int gx = gridDim.x, gy = gridDim.y, gz = gridDim.z;
    int S = gy * gz, nb = gx * S;
    if (((S & 7) == 0) && ((nb & 7) == 0)) {
      int L = bx + gx * (by + gy * bz);
      int xcd = L & 7, m = L >> 3, spx = S >> 3;
      int col = m % gx, sl = m / gx;
      int strip = xcd * spx + sl;
      bx = col; by = strip % gy; bz = strip / gy;
    }
  }

  const bf16* Ab = A + (size_t)bz * a_zstride;
  const bf16* Bb = BT + (size_t)bz * b_zstride;
  size_t row0 = (size_t)by * 128;
  size_t col0 = (size_t)bx * 128;

  const bf16* ga = Ab + (row0 + (t >> 2)) * (size_t)lda + (t & 3) * 8;
  const bf16* gb = Bb + (col0 + (t >> 2)) * (size_t)ldb + (t & 3) * 8;
  bf16* la = lds_a + t * 8;
  bf16* lb = lds_b + t * 8;

  f32x4 acc[4][4] = {};
  int lane = t & 63;
  int w = t >> 6;
  int wm = (w & 1) * 64, wn = (w >> 1) * 64;
  int lr = lane & 15, lq = lane >> 4;
  const int a_off0 = (wm + lr) * 32 + lq * 8;
  const int b_off0 = (wn + lr) * 32 + lq * 8;

  for (int k0 = 0; k0 < K; k0 += 32) {
    load_lds16(ga, la);
    load_lds16(ga + 64 * (size_t)lda, la + 64 * 32);
    load_lds16(gb, lb);
    load_lds16(gb + 64 * (size_t)ldb, lb + 64 * 32);
    ga += 32;
    gb += 32;
    __syncthreads();

    bf16x8 af[4], bfr[4];
#pragma unroll
    for (int i = 0; i < 4; ++i)
      af[i] = *(const bf16x8*)&lds_a[a_off0 + i * 16 * 32];
#pragma unroll
    for (int j = 0; j < 4; ++j)
      bfr[j] = *(const bf16x8*)&lds_b[b_off0 + j * 16 * 32];
#pragma unroll
    for (int i = 0; i < 4; ++i)
#pragma unroll
      for (int j = 0; j < 4; ++j)
        acc[i][j] = __builtin_amdgcn_mfma_f32_16x16x32_bf16(af[i], bfr[j],
                                                            acc[i][j], 0, 0, 0);
    __syncthreads();
  }

  // epilogue: C/D layout col=lane&15, row=(lane>>4)*4+reg (m89/m91 verified)
  // column-pair packing: lanes (lr, lr^1) hold adjacent cols of same rows.
  size_t cbase = (size_t)bz * c_zflat + col0;
#pragma unroll
  for (int i = 0; i < 4; ++i) {
    size_t r = row0 + wm + i * 16 + lq * 4;
    float4 inv4 = make_float4(1.f, 1.f, 1.f, 1.f);
    if (MODE == 3) {
      float4 lv = *(const float4*)&lsum[(size_t)bz * lzs + r];
      inv4 = make_float4(1.f / lv.x, 1.f / lv.y, 1.f / lv.z, 1.f / lv.w);
    }
#pragma unroll
    for (int j = 0; j < 4; ++j) {
      size_t c = cbase + wn + j * 16 + lr;
#pragma unroll
      for (int reg = 0; reg < 4; ++reg) {
        float v = acc[i][j][reg];
        if (MODE == 3) {
          float iv = reg == 0 ? inv4.x : reg == 1 ? inv4.y : reg == 2 ? inv4.z
                                                                      : inv4.w;
          v *= iv;
        }
        float nb = __shfl_xor(v, 1);
        if ((lr & 1) == 0) {
          size_t idx = (r + reg) * (size_t)ldc + c;
          *(unsigned*)&((bf16*)Cout)[idx] = pack2(v, nb);
        }
      }
    }
  }
}

extern "C" void kernel_launch(void* const* d_in, const int* in_sizes, int n_in,
                              void* d_out, int out_size, void* d_ws,
                              size_t ws_size, hipStream_t stream) {
  const float* x = (const float*)d_in[0];    // [B, T, C] fp32
  const float* wgt = (const float*)d_in[1];  // [D, E] fp32
  float* out = (float*)d_out;                // [B, T, E] fp32

  // ws layout
  bf16* xbT = (bf16*)d_ws;                        // [B][C][T]    8 MB
  bf16* wbT = xbT + (size_t)B_ * C_ * T_;         // [E][D]      32 MB
  bf16* xh = wbT + (size_t)E_ * D_;               // [B][H][T][64] 8 MB
  bf16* Obuf = xh + (size_t)B_ * H_ * T_ * 64;    // [B*T][D]   128 MB
  float* lsum = (float*)(Obuf + (size_t)B_ * T_ * D_);  // [16][T] 128 KB
  bf16* P = (bf16*)(lsum + (size_t)16 * T_);      // [Hs][T][T] slab 128 MB
  bf16* partials = P;                             // reuse slab (67 MB, KZ=8)

  transpose_cast_kernel<<<dim3(C_ / 32, T_ / 32, B_), dim3(32, 8), 0, stream>>>(
      x, xbT, T_, C_);
  transpose_cast_kernel<<<dim3(E_ / 32, D_ / 32, 1), dim3(32, 8), 0, stream>>>(
      wgt, wbT, D_, E_);
  xh_cast_kernel<<<B_ * T_, 256, 0, stream>>>(x, xh);

  size_t fixed_bytes = ((size_t)B_ * C_ * T_ + (size_t)E_ * D_ +
                        (size_t)B_ * H_ * T_ * 64 + (size_t)B_ * T_ * D_) * 2 +
                       (size_t)16 * T_ * 4;
  int Hs = 16;
  while (Hs > 1 && fixed_bytes + (size_t)Hs * T_ * T_ * 2 > ws_size) Hs >>= 1;

  for (int b = 0; b < B_; ++b) {
    for (int h0 = 0; h0 < H_; h0 += Hs) {
      const bf16* xhb = xh + (size_t)(b * H_ + h0) * T_ * 64;
      hipMemsetAsync(lsum, 0, (size_t)Hs * T_ * sizeof(float), stream);
      scores_kernel<<<dim3(136, Hs), 256, 0, stream>>>(xhb, P, lsum);
      // O = (P @ xbT^T) / l
      gemm_bt_kernel<3, 1><<<dim3(C_ / 128, T_ / 128, Hs), 256, 0, stream>>>(
          P, (long long)T_ * T_, T_, xbT + (size_t)b * C_ * T_, 0LL, T_,
          (void*)(Obuf + (size_t)b * T_ * D_ + (size_t)h0 * C_), D_,
          (long long)C_, lsum, T_, T_);
    }
  }
  // proj: partials[z] = O[:, z*2048:(z+1)*2048] @ W[z*2048:(z+1)*2048, :]
  gemm_bt_kernel<1, 1><<<dim3(E_ / 128, (B_ * T_) / 128, KZ_), 256, 0,
                         stream>>>(Obuf, (long long)(D_ / KZ_), D_, wbT,
                                   (long long)(D_ / KZ_), D_, (void*)partials,
                                   E_, (long long)B_ * T_ * E_, nullptr, 0,
                                   D_ / KZ_);
  reduce_kernel<<<(B_ * T_ * E_ / 8 + 255) / 256, 256, 0, stream>>>(
      partials, out, B_ * T_ * E_ / 8);
}